// Round 16
// baseline (136.767 us; speedup 1.0000x reference)
//
#include <hip/hip_runtime.h>
#include <math.h>

#define NTOK 4096
#define DIM 256
#define NHID 64
#define NHEADS 4
#define KSEL 6            // K+1
#define ALPHA_LR 0.2f
#define LNEPS 1e-5f
#define BIGN 768          // xm(256) | xr(256) | Wh(4*64)
#define JSPLIT 32         // 4096 / 128 j-tiles

typedef __attribute__((ext_vector_type(4))) float f32x4;
typedef __attribute__((ext_vector_type(8))) short short8;
typedef __attribute__((ext_vector_type(8))) unsigned short us8;
typedef unsigned long long ull;

__device__ __forceinline__ float f4get(const float4& v, int k) {
    return (k == 0) ? v.x : (k == 1) ? v.y : (k == 2) ? v.z : v.w;
}

__device__ __forceinline__ void gload16(const void* g, void* l) {
    __builtin_amdgcn_global_load_lds(
        (const __attribute__((address_space(1))) void*)g,
        (__attribute__((address_space(3))) void*)l, 16, 0, 0);
}

// u64 sorted-ascending top-6 insert; lex (key,idx) order via packed (ord<<32|j).
#define INS6U(L, V) do { ull _v = (V); if (_v < (L)[5]) {                         \
        bool c4 = _v < (L)[4], c3 = _v < (L)[3], c2 = _v < (L)[2];                \
        bool c1 = _v < (L)[1], c0 = _v < (L)[0];                                  \
        (L)[5] = c4 ? (L)[4] : _v;                                                \
        if (c4) { (L)[4] = c3 ? (L)[3] : _v; }                                    \
        if (c3) { (L)[3] = c2 ? (L)[2] : _v; }                                    \
        if (c2) { (L)[2] = c1 ? (L)[1] : _v; }                                    \
        if (c1) { (L)[1] = c0 ? (L)[0] : _v; }                                    \
        if (c0) { (L)[0] = _v; } } } while (0)

// ---------------- repack: BigB[256][768] = [Wm | Wr | W heads], BigBias[768] ----
__global__ void repack_kernel(const float* __restrict__ Wm, const float* __restrict__ bm,
                              const float* __restrict__ W,  const float* __restrict__ Wr,
                              const float* __restrict__ br,
                              float* __restrict__ BigB, float* __restrict__ BigBias) {
    int tid = blockIdx.x * blockDim.x + threadIdx.x;
    int total = DIM * BIGN;
    for (int e = tid; e < total; e += gridDim.x * blockDim.x) {
        int k = e / BIGN, col = e - k * BIGN;
        float v;
        if (col < 256)      v = Wm[k * 256 + col];
        else if (col < 512) v = Wr[k * 256 + (col - 256)];
        else {
            int c = col - 512;
            int h = c >> 6, d = c & 63;
            v = W[(h * DIM + k) * NHID + d];
        }
        BigB[e] = v;
    }
    if (tid < BIGN) {
        float b = 0.f;
        if (tid < 256)      b = bm[tid];
        else if (tid < 512) b = br[tid - 256];
        BigBias[tid] = b;
    }
}

// ---------------- GEMM: BigC[4096][768] = x[4096][256] @ BigB + BigBias --------
#define GEMM_SA 36
__global__ __launch_bounds__(256) void gemm_kernel(const float* __restrict__ A,
        const float* __restrict__ B, const float* __restrict__ bias,
        float* __restrict__ C) {
    __shared__ float As[64][GEMM_SA];   // [row][k]  (32 k used, pad to 36)
    __shared__ float Bs[32][64];        // [k][j]
    const int t  = threadIdx.x;
    const int tx = t & 15, ty = t >> 4;
    const int i0 = blockIdx.x * 64;
    const int j0 = blockIdx.y * 64;
    float c[4][4] = {};
    for (int kc = 0; kc < DIM / 32; ++kc) {
        __syncthreads();
        #pragma unroll
        for (int p = 0; p < 2; ++p) {
            int f  = t + p * 256;
            int ra = f >> 3, ka = (f & 7) * 4;
            *(float4*)&As[ra][ka] =
                *(const float4*)&A[(size_t)(i0 + ra) * DIM + kc * 32 + ka];
            int kb = f >> 4, jb = (f & 15) * 4;
            *(float4*)&Bs[kb][jb] =
                *(const float4*)&B[(size_t)(kc * 32 + kb) * BIGN + j0 + jb];
        }
        __syncthreads();
        #pragma unroll
        for (int kq = 0; kq < 8; ++kq) {
            float4 a4[4], b4[4];
            #pragma unroll
            for (int ii = 0; ii < 4; ++ii) a4[ii] = *(const float4*)&As[ty * 4 + ii][kq * 4];
            #pragma unroll
            for (int kk = 0; kk < 4; ++kk) b4[kk] = *(const float4*)&Bs[kq * 4 + kk][tx * 4];
            #pragma unroll
            for (int ii = 0; ii < 4; ++ii)
                #pragma unroll
                for (int kk = 0; kk < 4; ++kk)
                    #pragma unroll
                    for (int jj = 0; jj < 4; ++jj)
                        c[ii][jj] = fmaf(f4get(a4[ii], kk), f4get(b4[kk], jj), c[ii][jj]);
        }
    }
    #pragma unroll
    for (int ii = 0; ii < 4; ++ii) {
        int r = i0 + ty * 4 + ii;
        float4 bv = *(const float4*)&bias[j0 + tx * 4];
        float4 o;
        o.x = c[ii][0] + bv.x; o.y = c[ii][1] + bv.y;
        o.z = c[ii][2] + bv.z; o.w = c[ii][3] + bv.w;
        *(float4*)&C[(size_t)r * BIGN + j0 + tx * 4] = o;
    }
}

// ---------------- sq[n], e1[h][n], e2[h][n] + xb=[hi|lo] convert (fused) -------
__global__ __launch_bounds__(256) void sq_e_kernel(const float* __restrict__ BigC,
        const float* __restrict__ a, float* __restrict__ sq,
        float* __restrict__ e1, float* __restrict__ e2,
        unsigned short* __restrict__ xb) {
    const int n = blockIdx.x;
    const int t = threadIdx.x;
    const int l = t & 63;
    __shared__ float red[4];
    float xm = BigC[(size_t)n * BIGN + t];
    // bf16 hi/lo split (RNE both) -> xb
    {
        unsigned int u = __float_as_uint(xm);
        unsigned int hb = (u + 0x7fffu + ((u >> 16) & 1u)) >> 16;
        float hf = __uint_as_float(hb << 16);
        float lf = xm - hf;
        unsigned int u2 = __float_as_uint(lf);
        unsigned int lb = (u2 + 0x7fffu + ((u2 >> 16) & 1u)) >> 16;
        xb[(size_t)n * 512 + t]       = (unsigned short)hb;
        xb[(size_t)n * 512 + 256 + t] = (unsigned short)lb;
    }
    // sq: wave shfl reduce + 4-way
    float v = xm * xm;
    #pragma unroll
    for (int s = 32; s > 0; s >>= 1) v += __shfl_down(v, s, 64);
    if (l == 0) red[t >> 6] = v;
    __syncthreads();
    if (t == 0) sq[n] = red[0] + red[1] + red[2] + red[3];
    // e1/e2 per head (wave == head)
    const int h = t >> 6, d = t & 63;
    float wh = BigC[(size_t)n * BIGN + 512 + t];
    float v1 = wh * a[h * 128 + d];
    float v2 = wh * a[h * 128 + 64 + d];
    #pragma unroll
    for (int s = 32; s > 0; s >>= 1) {
        v1 += __shfl_down(v1, s, 64);
        v2 += __shfl_down(v2, s, 64);
    }
    if (d == 0) { e1[h * NTOK + n] = v1; e2[h * NTOK + n] = v2; }
}

// ---------------- distance GEMM: concat-K bf16x3, T3/T4 pipelined (R12) --------
// R12-proven skeleton (99.6 us) + T1 XCD-chunked grid swizzle (latency-bound:
// keeps each XCD's B j-stripes resident in its 4MB L2 across the 64 i-blocks
// that share them; bijective since 2048 % 8 == 0).
// Tile 64i x 128j, 4 waves, 12 rounds of BK=64 (A'=[hi|lo|hi], B'=[hi|hi|lo]).
// LDS: 2 buffers x {A[64][64] 8KB + B[128][64] 16KB} = 48KB.
// Protocol: vmcnt(6) [r==11: vmcnt(0)] -> s_barrier -> compute(buf[cur]) ->
// lgkmcnt(0)+sched_barrier -> s_barrier -> STAGE(r+2 -> buf[cur]).
// XOR swizzle both-sides: src chunk (l&7)^(l>>3), read (4s+l>>4)^(l&7).
__global__ __launch_bounds__(256, 2) void dist_topk_kernel(
        const unsigned short* __restrict__ xb, const float* __restrict__ sq,
        float* __restrict__ candD, int* __restrict__ candI) {
    __shared__ __align__(16) unsigned char smem[49664];
    unsigned short* sh = (unsigned short*)smem;   // 2 x 12288 shorts (48KB)
    float* Kd  = (float*)smem;                    // [32][132] epilogue overlay
    float* sqs = (float*)(smem + 49152);          // [128]

    const int t = threadIdx.x;
    const int l = t & 63;
    const int w = t >> 6;
    const int wi = w >> 1, wj = w & 1;            // wave tile 32i x 64j
    // T1: XCD-chunked bijective remap (8 XCDs, 2048 blocks)
    const int Lid = blockIdx.y * 64 + blockIdx.x;
    const int nid = (Lid & 7) * 256 + (Lid >> 3);
    const int i0 = (nid & 63) * 64;
    const int by = nid >> 6;
    const int j0 = by * 128;
    const int arow = l >> 3;
    const int csrc = ((l & 7) ^ (l >> 3)) * 8;    // pre-swizzled source chunk

    if (t < 32) ((float4*)sqs)[t] = ((const float4*)(sq + j0))[t];

    f32x4 acc[2][4] = {};

    #define STAGE(R, PAR) do {                                                    \
        const int _ac = (((R) < 8) ? (R) : (R) - 8) * 64;                         \
        const int _bc = (((R) < 4) ? (R) : (R) - 4) * 64;                         \
        unsigned short* _SA = sh + (PAR) * 12288;                                 \
        unsigned short* _SB = _SA + 4096;                                         \
        _Pragma("unroll")                                                         \
        for (int q = 0; q < 2; ++q) {                                             \
            const int rb = (w * 2 + q) * 8;                                       \
            gload16(xb + (size_t)(i0 + rb + arow) * 512 + _ac + csrc,             \
                    _SA + rb * 64);                                               \
        }                                                                         \
        _Pragma("unroll")                                                         \
        for (int q = 0; q < 4; ++q) {                                             \
            const int rb = (w * 4 + q) * 8;                                       \
            gload16(xb + (size_t)(j0 + rb + arow) * 512 + _bc + csrc,             \
                    _SB + rb * 64);                                               \
        }                                                                         \
    } while (0)

    // prologue: rounds 0 and 1 in flight
    STAGE(0, 0);
    STAGE(1, 1);

    #pragma unroll
    for (int r = 0; r < 12; ++r) {
        const int cur = r & 1;
        if (r < 11) { asm volatile("s_waitcnt vmcnt(6)" ::: "memory"); }
        else        { asm volatile("s_waitcnt vmcnt(0)" ::: "memory"); }
        __builtin_amdgcn_s_barrier();           // all waves' loads for buf[cur] landed
        {
            unsigned short* SA = sh + cur * 12288;
            unsigned short* SB = SA + 4096;
            #pragma unroll
            for (int s = 0; s < 2; ++s) {
                const int rsl = ((s * 4 + (l >> 4)) ^ (l & 7)) * 8;
                short8 af[2], bf[4];
                #pragma unroll
                for (int ti = 0; ti < 2; ++ti)
                    af[ti] = *(const short8*)(SA + (wi * 32 + ti * 16 + (l & 15)) * 64 + rsl);
                #pragma unroll
                for (int tj = 0; tj < 4; ++tj)
                    bf[tj] = *(const short8*)(SB + (wj * 64 + tj * 16 + (l & 15)) * 64 + rsl);
                #pragma unroll
                for (int ti = 0; ti < 2; ++ti)
                    #pragma unroll
                    for (int tj = 0; tj < 4; ++tj)
                        acc[ti][tj] = __builtin_amdgcn_mfma_f32_16x16x32_bf16(
                            af[ti], bf[tj], acc[ti][tj], 0, 0, 0);
            }
        }
        asm volatile("s_waitcnt lgkmcnt(0)" ::: "memory");  // my ds_reads complete
        __builtin_amdgcn_sched_barrier(0);
        __builtin_amdgcn_s_barrier();           // all waves done reading buf[cur]
        if (r + 2 < 12) STAGE(r + 2, cur);      // overwrite buf[cur] for round r+2
    }
    #undef STAGE

    // ---- epilogue: 2 passes of 32 i-rows; Kd overlay; u64 top-6 ---------------
    #pragma unroll
    for (int p = 0; p < 2; ++p) {
        __syncthreads();
        if (wi == p) {
            #pragma unroll
            for (int ti = 0; ti < 2; ++ti)
                #pragma unroll
                for (int tj = 0; tj < 4; ++tj) {
                    const int jb = wj * 64 + tj * 16 + (l & 15);
                    #pragma unroll
                    for (int r2 = 0; r2 < 4; ++r2)
                        Kd[(ti * 16 + ((l >> 4) << 2) + r2) * 132 + jb] = acc[ti][tj][r2];
                }
        }
        __syncthreads();
        {
            const int lr = t >> 3;
            const int jsl = (t & 7) * 16;
            ull L[6] = {~0ull, ~0ull, ~0ull, ~0ull, ~0ull, ~0ull};
            #pragma unroll
            for (int q4 = 0; q4 < 4; ++q4) {
                float4 dv = *(const float4*)&Kd[lr * 132 + jsl + q4 * 4];
                #pragma unroll
                for (int r2 = 0; r2 < 4; ++r2) {
                    const int jb = jsl + q4 * 4 + r2;
                    float key = sqs[jb] - 2.0f * f4get(dv, r2);
                    unsigned int u = __float_as_uint(key);
                    unsigned int o = (u & 0x80000000u) ? ~u : (u | 0x80000000u);
                    ull cand = ((ull)o << 32) | (unsigned int)(j0 + jb);
                    INS6U(L, cand);
                }
            }
            #pragma unroll
            for (int s2 = 1; s2 <= 4; s2 <<= 1) {
                ull ov[6];
                #pragma unroll
                for (int k = 0; k < 6; ++k) ov[k] = __shfl_xor(L[k], s2, 8);
                #pragma unroll
                for (int k = 0; k < 6; ++k) { INS6U(L, ov[k]); }
            }
            if ((t & 7) == 0) {
                const int r2 = p * 32 + lr;
                size_t ob = ((size_t)(i0 + r2) * JSPLIT + by) * KSEL;
                #pragma unroll
                for (int k = 0; k < 6; ++k) {
                    unsigned int o = (unsigned int)(L[k] >> 32);
                    unsigned int u = (o & 0x80000000u) ? (o ^ 0x80000000u) : ~o;
                    candD[ob + k] = __uint_as_float(u);
                    candI[ob + k] = (int)(L[k] & 0xffffffffu);
                }
            }
        }
    }
}

// ---------------- attention + residual + LN + ELU + out projection -------------
// merge_kernel fused in: wave-0 lanes 0..31 merge the 32 per-range sorted
// 6-lists for row i (exact lex (d,idx) semantics), write sidx to LDS.
__global__ __launch_bounds__(256) void final_kernel(const float* __restrict__ BigC,
        const float* __restrict__ e1, const float* __restrict__ e2,
        const float* __restrict__ candD, const int* __restrict__ candI,
        const float* __restrict__ ln_g, const float* __restrict__ ln_b,
        const float* __restrict__ Wo, const float* __restrict__ bo,
        float* __restrict__ out) {
    const int i = blockIdx.x;
    const int t = threadIdx.x;
    const int h = t >> 6;
    const int l = t & 63;
    __shared__ int sidx[KSEL];
    __shared__ float red[4];
    if (t < 32) {
        const int lg = t;
        size_t base = ((size_t)i * JSPLIT + lg) * KSEL;
        float d[KSEL]; int ix[KSEL];
        #pragma unroll
        for (int k = 0; k < KSEL; ++k) { d[k] = candD[base + k]; ix[k] = candI[base + k]; }
        float lastD = -3.0e38f; int lastI = -1;
        #pragma unroll
        for (int k = 0; k < KSEL; ++k) {
            float bdv = 3.4e38f; int biv = 0x7fffffff;
            #pragma unroll
            for (int q = 0; q < KSEL; ++q) {
                bool after  = (d[q] > lastD) || (d[q] == lastD && ix[q] > lastI);
                bool better = (d[q] < bdv)  || (d[q] == bdv  && ix[q] < biv);
                if (after && better) { bdv = d[q]; biv = ix[q]; }
            }
            #pragma unroll
            for (int s = 1; s < 32; s <<= 1) {
                float od = __shfl_xor(bdv, s, 32);
                int   oi = __shfl_xor(biv, s, 32);
                if (od < bdv || (od == bdv && oi < biv)) { bdv = od; biv = oi; }
            }
            if (lg == 0) sidx[k] = biv;
            lastD = bdv; lastI = biv;
        }
    }
    __syncthreads();
    const float e1i = e1[h * NTOK + i];
    float ev[KSEL];
    float m = -3.0e38f;
    #pragma unroll
    for (int k = 0; k < KSEL; ++k) {
        float v = e1i + e2[h * NTOK + sidx[k]];
        v = (v > 0.f) ? v : ALPHA_LR * v;
        ev[k] = v;
        m = fmaxf(m, v);
    }
    float ssum = 0.f;
    #pragma unroll
    for (int k = 0; k < KSEL; ++k) { ev[k] = expf(ev[k] - m); ssum += ev[k]; }
    float agg = 0.f;
    #pragma unroll
    for (int k = 0; k < KSEL; ++k)
        agg += ev[k] * BigC[(size_t)sidx[k] * BIGN + 512 + t];
    agg /= ssum;
    float hv = agg + BigC[(size_t)i * BIGN + 256 + t];
    // mean
    float v = hv;
    #pragma unroll
    for (int s = 32; s > 0; s >>= 1) v += __shfl_down(v, s, 64);
    if (l == 0) red[h] = v;
    __syncthreads();
    float mu = (red[0] + red[1] + red[2] + red[3]) * (1.f / 256.f);
    __syncthreads();
    // variance
    float dv = hv - mu;
    v = dv * dv;
    #pragma unroll
    for (int s = 32; s > 0; s >>= 1) v += __shfl_down(v, s, 64);
    if (l == 0) red[h] = v;
    __syncthreads();
    float var = (red[0] + red[1] + red[2] + red[3]) * (1.f / 256.f);
    __syncthreads();
    float nv  = dv / sqrtf(var + LNEPS) * ln_g[t] + ln_b[t];
    float act = (nv > 0.f) ? nv : expm1f(nv);
    // out0
    v = act * Wo[t * 2 + 0];
    #pragma unroll
    for (int s = 32; s > 0; s >>= 1) v += __shfl_down(v, s, 64);
    if (l == 0) red[h] = v;
    __syncthreads();
    float o0 = red[0] + red[1] + red[2] + red[3];
    __syncthreads();
    // out1
    v = act * Wo[t * 2 + 1];
    #pragma unroll
    for (int s = 32; s > 0; s >>= 1) v += __shfl_down(v, s, 64);
    if (l == 0) red[h] = v;
    __syncthreads();
    if (t == 0) {
        out[i * 2 + 0] = o0 + bo[0];
        out[i * 2 + 1] = red[0] + red[1] + red[2] + red[3] + bo[1];
    }
}

extern "C" void kernel_launch(void* const* d_in, const int* in_sizes, int n_in,
                              void* d_out, int out_size, void* d_ws, size_t ws_size,
                              hipStream_t stream) {
    (void)in_sizes; (void)n_in; (void)out_size; (void)ws_size;
    const float* x    = (const float*)d_in[0];
    const float* Wm   = (const float*)d_in[1];
    const float* bm   = (const float*)d_in[2];
    const float* W    = (const float*)d_in[3];
    const float* a    = (const float*)d_in[4];
    const float* Wr   = (const float*)d_in[5];
    const float* br   = (const float*)d_in[6];
    const float* ln_g = (const float*)d_in[7];
    const float* ln_b = (const float*)d_in[8];
    const float* Wo   = (const float*)d_in[9];
    const float* bo   = (const float*)d_in[10];
    float* out = (float*)d_out;

    char* ws = (char*)d_ws;
    float*          BigB    = (float*)(ws + 0);              // 786432 B
    float*          BigBias = (float*)(ws + 786432);         // -> 789504
    float*          BigC    = (float*)(ws + 789504);         // -> 13372416
    float*          sq      = (float*)(ws + 13372416);       // -> 13388800
    float*          e1      = (float*)(ws + 13388800);       // -> 13454336
    float*          e2      = (float*)(ws + 13454336);       // -> 13519872
    unsigned short* xb      = (unsigned short*)(ws + 13519872); // 4096*512*2 -> 17714176
    float*          candD   = (float*)(ws + 17714176);       // 4096*32*6*4 -> 20859904
    int*            candI   = (int*)  (ws + 20859904);       // -> 24005632

    hipLaunchKernelGGL(repack_kernel, dim3(768), dim3(256), 0, stream,
                       Wm, bm, W, Wr, br, BigB, BigBias);
    hipLaunchKernelGGL(gemm_kernel, dim3(64, 12), dim3(256), 0, stream,
                       x, BigB, BigBias, BigC);
    hipLaunchKernelGGL(sq_e_kernel, dim3(4096), dim3(256), 0, stream,
                       BigC, a, sq, e1, e2, xb);
    hipLaunchKernelGGL(dist_topk_kernel, dim3(64, 32), dim3(256), 0, stream,
                       xb, sq, candD, candI);
    hipLaunchKernelGGL(final_kernel, dim3(4096), dim3(256), 0, stream,
                       BigC, e1, e2, candD, candI, ln_g, ln_b, Wo, bo, out);
}

// Round 17
// 135.159 us; speedup vs baseline: 1.0119x; 1.0119x over previous
//
#include <hip/hip_runtime.h>
#include <math.h>

#define NTOK 4096
#define DIM 256
#define NHID 64
#define NHEADS 4
#define KSEL 6            // K+1
#define ALPHA_LR 0.2f
#define LNEPS 1e-5f
#define BIGN 768          // xm(256) | xr(256) | Wh(4*64)
#define JSPLIT 32         // 4096 / 128 j-tiles

typedef __attribute__((ext_vector_type(4))) float f32x4;
typedef __attribute__((ext_vector_type(8))) short short8;
typedef __attribute__((ext_vector_type(8))) unsigned short us8;
typedef unsigned long long ull;

__device__ __forceinline__ float f4get(const float4& v, int k) {
    return (k == 0) ? v.x : (k == 1) ? v.y : (k == 2) ? v.z : v.w;
}

__device__ __forceinline__ void gload16(const void* g, void* l) {
    __builtin_amdgcn_global_load_lds(
        (const __attribute__((address_space(1))) void*)g,
        (__attribute__((address_space(3))) void*)l, 16, 0, 0);
}

// u64 sorted-ascending top-6 insert; lex (key,idx) order via packed (ord<<32|j).
#define INS6U(L, V) do { ull _v = (V); if (_v < (L)[5]) {                         \
        bool c4 = _v < (L)[4], c3 = _v < (L)[3], c2 = _v < (L)[2];                \
        bool c1 = _v < (L)[1], c0 = _v < (L)[0];                                  \
        (L)[5] = c4 ? (L)[4] : _v;                                                \
        if (c4) { (L)[4] = c3 ? (L)[3] : _v; }                                    \
        if (c3) { (L)[3] = c2 ? (L)[2] : _v; }                                    \
        if (c2) { (L)[2] = c1 ? (L)[1] : _v; }                                    \
        if (c1) { (L)[1] = c0 ? (L)[0] : _v; }                                    \
        if (c0) { (L)[0] = _v; } } } while (0)

// ---------------- repack: BigB[256][768] = [Wm | Wr | W heads], BigBias[768] ----
__global__ void repack_kernel(const float* __restrict__ Wm, const float* __restrict__ bm,
                              const float* __restrict__ W,  const float* __restrict__ Wr,
                              const float* __restrict__ br,
                              float* __restrict__ BigB, float* __restrict__ BigBias) {
    int tid = blockIdx.x * blockDim.x + threadIdx.x;
    int total = DIM * BIGN;
    for (int e = tid; e < total; e += gridDim.x * blockDim.x) {
        int k = e / BIGN, col = e - k * BIGN;
        float v;
        if (col < 256)      v = Wm[k * 256 + col];
        else if (col < 512) v = Wr[k * 256 + (col - 256)];
        else {
            int c = col - 512;
            int h = c >> 6, d = c & 63;
            v = W[(h * DIM + k) * NHID + d];
        }
        BigB[e] = v;
    }
    if (tid < BIGN) {
        float b = 0.f;
        if (tid < 256)      b = bm[tid];
        else if (tid < 512) b = br[tid - 256];
        BigBias[tid] = b;
    }
}

// ---------------- GEMM: BigC[4096][768] = x[4096][256] @ BigB + BigBias --------
#define GEMM_SA 36
__global__ __launch_bounds__(256) void gemm_kernel(const float* __restrict__ A,
        const float* __restrict__ B, const float* __restrict__ bias,
        float* __restrict__ C) {
    __shared__ float As[64][GEMM_SA];   // [row][k]  (32 k used, pad to 36)
    __shared__ float Bs[32][64];        // [k][j]
    const int t  = threadIdx.x;
    const int tx = t & 15, ty = t >> 4;
    const int i0 = blockIdx.x * 64;
    const int j0 = blockIdx.y * 64;
    float c[4][4] = {};
    for (int kc = 0; kc < DIM / 32; ++kc) {
        __syncthreads();
        #pragma unroll
        for (int p = 0; p < 2; ++p) {
            int f  = t + p * 256;
            int ra = f >> 3, ka = (f & 7) * 4;
            *(float4*)&As[ra][ka] =
                *(const float4*)&A[(size_t)(i0 + ra) * DIM + kc * 32 + ka];
            int kb = f >> 4, jb = (f & 15) * 4;
            *(float4*)&Bs[kb][jb] =
                *(const float4*)&B[(size_t)(kc * 32 + kb) * BIGN + j0 + jb];
        }
        __syncthreads();
        #pragma unroll
        for (int kq = 0; kq < 8; ++kq) {
            float4 a4[4], b4[4];
            #pragma unroll
            for (int ii = 0; ii < 4; ++ii) a4[ii] = *(const float4*)&As[ty * 4 + ii][kq * 4];
            #pragma unroll
            for (int kk = 0; kk < 4; ++kk) b4[kk] = *(const float4*)&Bs[kq * 4 + kk][tx * 4];
            #pragma unroll
            for (int ii = 0; ii < 4; ++ii)
                #pragma unroll
                for (int kk = 0; kk < 4; ++kk)
                    #pragma unroll
                    for (int jj = 0; jj < 4; ++jj)
                        c[ii][jj] = fmaf(f4get(a4[ii], kk), f4get(b4[kk], jj), c[ii][jj]);
        }
    }
    #pragma unroll
    for (int ii = 0; ii < 4; ++ii) {
        int r = i0 + ty * 4 + ii;
        float4 bv = *(const float4*)&bias[j0 + tx * 4];
        float4 o;
        o.x = c[ii][0] + bv.x; o.y = c[ii][1] + bv.y;
        o.z = c[ii][2] + bv.z; o.w = c[ii][3] + bv.w;
        *(float4*)&C[(size_t)r * BIGN + j0 + tx * 4] = o;
    }
}

// ---------------- sq[n], e1[h][n], e2[h][n] + xb=[hi|lo] convert (fused) -------
__global__ __launch_bounds__(256) void sq_e_kernel(const float* __restrict__ BigC,
        const float* __restrict__ a, float* __restrict__ sq,
        float* __restrict__ e1, float* __restrict__ e2,
        unsigned short* __restrict__ xb) {
    const int n = blockIdx.x;
    const int t = threadIdx.x;
    const int l = t & 63;
    __shared__ float red[4];
    float xm = BigC[(size_t)n * BIGN + t];
    // bf16 hi/lo split (RNE both) -> xb
    {
        unsigned int u = __float_as_uint(xm);
        unsigned int hb = (u + 0x7fffu + ((u >> 16) & 1u)) >> 16;
        float hf = __uint_as_float(hb << 16);
        float lf = xm - hf;
        unsigned int u2 = __float_as_uint(lf);
        unsigned int lb = (u2 + 0x7fffu + ((u2 >> 16) & 1u)) >> 16;
        xb[(size_t)n * 512 + t]       = (unsigned short)hb;
        xb[(size_t)n * 512 + 256 + t] = (unsigned short)lb;
    }
    // sq: wave shfl reduce + 4-way
    float v = xm * xm;
    #pragma unroll
    for (int s = 32; s > 0; s >>= 1) v += __shfl_down(v, s, 64);
    if (l == 0) red[t >> 6] = v;
    __syncthreads();
    if (t == 0) sq[n] = red[0] + red[1] + red[2] + red[3];
    // e1/e2 per head (wave == head)
    const int h = t >> 6, d = t & 63;
    float wh = BigC[(size_t)n * BIGN + 512 + t];
    float v1 = wh * a[h * 128 + d];
    float v2 = wh * a[h * 128 + 64 + d];
    #pragma unroll
    for (int s = 32; s > 0; s >>= 1) {
        v1 += __shfl_down(v1, s, 64);
        v2 += __shfl_down(v2, s, 64);
    }
    if (d == 0) { e1[h * NTOK + n] = v1; e2[h * NTOK + n] = v2; }
}

// ---------------- distance GEMM: concat-K bf16x3, T3/T4 pipelined (R12) --------
// Exact R12 skeleton (99.6 us proven): natural blockIdx mapping (R16's XCD
// swizzle tripled FETCH_SIZE -> reverted). Tile 64i x 128j, 4 waves, 12 rounds
// of BK=64 (A'=[hi|lo|hi], B'=[hi|hi|lo] from xb=[hi|lo] via column remap).
// LDS: 2 buffers x {A[64][64] 8KB + B[128][64] 16KB} = 48KB.
// Protocol: vmcnt(6) [r==11: vmcnt(0)] -> s_barrier -> compute(buf[cur]) ->
// lgkmcnt(0)+sched_barrier -> s_barrier -> STAGE(r+2 -> buf[cur]).
// XOR swizzle both-sides: src chunk (l&7)^(l>>3), read (4s+l>>4)^(l&7).
__global__ __launch_bounds__(256, 2) void dist_topk_kernel(
        const unsigned short* __restrict__ xb, const float* __restrict__ sq,
        float* __restrict__ candD, int* __restrict__ candI) {
    __shared__ __align__(16) unsigned char smem[49664];
    unsigned short* sh = (unsigned short*)smem;   // 2 x 12288 shorts (48KB)
    float* Kd  = (float*)smem;                    // [32][132] epilogue overlay
    float* sqs = (float*)(smem + 49152);          // [128]

    const int t = threadIdx.x;
    const int l = t & 63;
    const int w = t >> 6;
    const int wi = w >> 1, wj = w & 1;            // wave tile 32i x 64j
    const int i0 = blockIdx.x * 64;
    const int j0 = blockIdx.y * 128;
    const int arow = l >> 3;
    const int csrc = ((l & 7) ^ (l >> 3)) * 8;    // pre-swizzled source chunk

    if (t < 32) ((float4*)sqs)[t] = ((const float4*)(sq + j0))[t];

    f32x4 acc[2][4] = {};

    #define STAGE(R, PAR) do {                                                    \
        const int _ac = (((R) < 8) ? (R) : (R) - 8) * 64;                         \
        const int _bc = (((R) < 4) ? (R) : (R) - 4) * 64;                         \
        unsigned short* _SA = sh + (PAR) * 12288;                                 \
        unsigned short* _SB = _SA + 4096;                                         \
        _Pragma("unroll")                                                         \
        for (int q = 0; q < 2; ++q) {                                             \
            const int rb = (w * 2 + q) * 8;                                       \
            gload16(xb + (size_t)(i0 + rb + arow) * 512 + _ac + csrc,             \
                    _SA + rb * 64);                                               \
        }                                                                         \
        _Pragma("unroll")                                                         \
        for (int q = 0; q < 4; ++q) {                                             \
            const int rb = (w * 4 + q) * 8;                                       \
            gload16(xb + (size_t)(j0 + rb + arow) * 512 + _bc + csrc,             \
                    _SB + rb * 64);                                               \
        }                                                                         \
    } while (0)

    // prologue: rounds 0 and 1 in flight
    STAGE(0, 0);
    STAGE(1, 1);

    #pragma unroll
    for (int r = 0; r < 12; ++r) {
        const int cur = r & 1;
        if (r < 11) { asm volatile("s_waitcnt vmcnt(6)" ::: "memory"); }
        else        { asm volatile("s_waitcnt vmcnt(0)" ::: "memory"); }
        __builtin_amdgcn_s_barrier();           // all waves' loads for buf[cur] landed
        {
            unsigned short* SA = sh + cur * 12288;
            unsigned short* SB = SA + 4096;
            #pragma unroll
            for (int s = 0; s < 2; ++s) {
                const int rsl = ((s * 4 + (l >> 4)) ^ (l & 7)) * 8;
                short8 af[2], bf[4];
                #pragma unroll
                for (int ti = 0; ti < 2; ++ti)
                    af[ti] = *(const short8*)(SA + (wi * 32 + ti * 16 + (l & 15)) * 64 + rsl);
                #pragma unroll
                for (int tj = 0; tj < 4; ++tj)
                    bf[tj] = *(const short8*)(SB + (wj * 64 + tj * 16 + (l & 15)) * 64 + rsl);
                #pragma unroll
                for (int ti = 0; ti < 2; ++ti)
                    #pragma unroll
                    for (int tj = 0; tj < 4; ++tj)
                        acc[ti][tj] = __builtin_amdgcn_mfma_f32_16x16x32_bf16(
                            af[ti], bf[tj], acc[ti][tj], 0, 0, 0);
            }
        }
        asm volatile("s_waitcnt lgkmcnt(0)" ::: "memory");  // my ds_reads complete
        __builtin_amdgcn_sched_barrier(0);
        __builtin_amdgcn_s_barrier();           // all waves done reading buf[cur]
        if (r + 2 < 12) STAGE(r + 2, cur);      // overwrite buf[cur] for round r+2
    }
    #undef STAGE

    // ---- epilogue: 2 passes of 32 i-rows; Kd overlay; u64 top-6 ---------------
    #pragma unroll
    for (int p = 0; p < 2; ++p) {
        __syncthreads();
        if (wi == p) {
            #pragma unroll
            for (int ti = 0; ti < 2; ++ti)
                #pragma unroll
                for (int tj = 0; tj < 4; ++tj) {
                    const int jb = wj * 64 + tj * 16 + (l & 15);
                    #pragma unroll
                    for (int r2 = 0; r2 < 4; ++r2)
                        Kd[(ti * 16 + ((l >> 4) << 2) + r2) * 132 + jb] = acc[ti][tj][r2];
                }
        }
        __syncthreads();
        {
            const int lr = t >> 3;
            const int jsl = (t & 7) * 16;
            ull L[6] = {~0ull, ~0ull, ~0ull, ~0ull, ~0ull, ~0ull};
            #pragma unroll
            for (int q4 = 0; q4 < 4; ++q4) {
                float4 dv = *(const float4*)&Kd[lr * 132 + jsl + q4 * 4];
                #pragma unroll
                for (int r2 = 0; r2 < 4; ++r2) {
                    const int jb = jsl + q4 * 4 + r2;
                    float key = sqs[jb] - 2.0f * f4get(dv, r2);
                    unsigned int u = __float_as_uint(key);
                    unsigned int o = (u & 0x80000000u) ? ~u : (u | 0x80000000u);
                    ull cand = ((ull)o << 32) | (unsigned int)(j0 + jb);
                    INS6U(L, cand);
                }
            }
            #pragma unroll
            for (int s2 = 1; s2 <= 4; s2 <<= 1) {
                ull ov[6];
                #pragma unroll
                for (int k = 0; k < 6; ++k) ov[k] = __shfl_xor(L[k], s2, 8);
                #pragma unroll
                for (int k = 0; k < 6; ++k) { INS6U(L, ov[k]); }
            }
            if ((t & 7) == 0) {
                const int r2 = p * 32 + lr;
                size_t ob = ((size_t)(i0 + r2) * JSPLIT + blockIdx.y) * KSEL;
                #pragma unroll
                for (int k = 0; k < 6; ++k) {
                    unsigned int o = (unsigned int)(L[k] >> 32);
                    unsigned int u = (o & 0x80000000u) ? (o ^ 0x80000000u) : ~o;
                    candD[ob + k] = __uint_as_float(u);
                    candI[ob + k] = (int)(L[k] & 0xffffffffu);
                }
            }
        }
    }
}

// ---------------- attention + residual + LN + ELU + out projection -------------
// merge fused in: wave-0 lanes 0..31 merge the 32 per-range sorted 6-lists for
// row i (exact lex (d,idx) semantics), write sidx to LDS.
__global__ __launch_bounds__(256) void final_kernel(const float* __restrict__ BigC,
        const float* __restrict__ e1, const float* __restrict__ e2,
        const float* __restrict__ candD, const int* __restrict__ candI,
        const float* __restrict__ ln_g, const float* __restrict__ ln_b,
        const float* __restrict__ Wo, const float* __restrict__ bo,
        float* __restrict__ out) {
    const int i = blockIdx.x;
    const int t = threadIdx.x;
    const int h = t >> 6;
    const int l = t & 63;
    __shared__ int sidx[KSEL];
    __shared__ float red[4];
    if (t < 32) {
        const int lg = t;
        size_t base = ((size_t)i * JSPLIT + lg) * KSEL;
        float d[KSEL]; int ix[KSEL];
        #pragma unroll
        for (int k = 0; k < KSEL; ++k) { d[k] = candD[base + k]; ix[k] = candI[base + k]; }
        float lastD = -3.0e38f; int lastI = -1;
        #pragma unroll
        for (int k = 0; k < KSEL; ++k) {
            float bdv = 3.4e38f; int biv = 0x7fffffff;
            #pragma unroll
            for (int q = 0; q < KSEL; ++q) {
                bool after  = (d[q] > lastD) || (d[q] == lastD && ix[q] > lastI);
                bool better = (d[q] < bdv)  || (d[q] == bdv  && ix[q] < biv);
                if (after && better) { bdv = d[q]; biv = ix[q]; }
            }
            #pragma unroll
            for (int s = 1; s < 32; s <<= 1) {
                float od = __shfl_xor(bdv, s, 32);
                int   oi = __shfl_xor(biv, s, 32);
                if (od < bdv || (od == bdv && oi < biv)) { bdv = od; biv = oi; }
            }
            if (lg == 0) sidx[k] = biv;
            lastD = bdv; lastI = biv;
        }
    }
    __syncthreads();
    const float e1i = e1[h * NTOK + i];
    float ev[KSEL];
    float m = -3.0e38f;
    #pragma unroll
    for (int k = 0; k < KSEL; ++k) {
        float v = e1i + e2[h * NTOK + sidx[k]];
        v = (v > 0.f) ? v : ALPHA_LR * v;
        ev[k] = v;
        m = fmaxf(m, v);
    }
    float ssum = 0.f;
    #pragma unroll
    for (int k = 0; k < KSEL; ++k) { ev[k] = expf(ev[k] - m); ssum += ev[k]; }
    float agg = 0.f;
    #pragma unroll
    for (int k = 0; k < KSEL; ++k)
        agg += ev[k] * BigC[(size_t)sidx[k] * BIGN + 512 + t];
    agg /= ssum;
    float hv = agg + BigC[(size_t)i * BIGN + 256 + t];
    // mean
    float v = hv;
    #pragma unroll
    for (int s = 32; s > 0; s >>= 1) v += __shfl_down(v, s, 64);
    if (l == 0) red[h] = v;
    __syncthreads();
    float mu = (red[0] + red[1] + red[2] + red[3]) * (1.f / 256.f);
    __syncthreads();
    // variance
    float dv = hv - mu;
    v = dv * dv;
    #pragma unroll
    for (int s = 32; s > 0; s >>= 1) v += __shfl_down(v, s, 64);
    if (l == 0) red[h] = v;
    __syncthreads();
    float var = (red[0] + red[1] + red[2] + red[3]) * (1.f / 256.f);
    __syncthreads();
    float nv  = dv / sqrtf(var + LNEPS) * ln_g[t] + ln_b[t];
    float act = (nv > 0.f) ? nv : expm1f(nv);
    // out0
    v = act * Wo[t * 2 + 0];
    #pragma unroll
    for (int s = 32; s > 0; s >>= 1) v += __shfl_down(v, s, 64);
    if (l == 0) red[h] = v;
    __syncthreads();
    float o0 = red[0] + red[1] + red[2] + red[3];
    __syncthreads();
    // out1
    v = act * Wo[t * 2 + 1];
    #pragma unroll
    for (int s = 32; s > 0; s >>= 1) v += __shfl_down(v, s, 64);
    if (l == 0) red[h] = v;
    __syncthreads();
    if (t == 0) {
        out[i * 2 + 0] = o0 + bo[0];
        out[i * 2 + 1] = red[0] + red[1] + red[2] + red[3] + bo[1];
    }
}

extern "C" void kernel_launch(void* const* d_in, const int* in_sizes, int n_in,
                              void* d_out, int out_size, void* d_ws, size_t ws_size,
                              hipStream_t stream) {
    (void)in_sizes; (void)n_in; (void)out_size; (void)ws_size;
    const float* x    = (const float*)d_in[0];
    const float* Wm   = (const float*)d_in[1];
    const float* bm   = (const float*)d_in[2];
    const float* W    = (const float*)d_in[3];
    const float* a    = (const float*)d_in[4];
    const float* Wr   = (const float*)d_in[5];
    const float* br   = (const float*)d_in[6];
    const float* ln_g = (const float*)d_in[7];
    const float* ln_b = (const float*)d_in[8];
    const float* Wo   = (const float*)d_in[9];
    const float* bo   = (const float*)d_in[10];
    float* out = (float*)d_out;

    char* ws = (char*)d_ws;
    float*          BigB    = (float*)(ws + 0);              // 786432 B
    float*          BigBias = (float*)(ws + 786432);         // -> 789504
    float*          BigC    = (float*)(ws + 789504);         // -> 13372416
    float*          sq      = (float*)(ws + 13372416);       // -> 13388800
    float*          e1      = (float*)(ws + 13388800);       // -> 13454336
    float*          e2      = (float*)(ws + 13454336);       // -> 13519872
    unsigned short* xb      = (unsigned short*)(ws + 13519872); // 4096*512*2 -> 17714176
    float*          candD   = (float*)(ws + 17714176);       // 4096*32*6*4 -> 20859904
    int*            candI   = (int*)  (ws + 20859904);       // -> 24005632

    hipLaunchKernelGGL(repack_kernel, dim3(768), dim3(256), 0, stream,
                       Wm, bm, W, Wr, br, BigB, BigBias);
    hipLaunchKernelGGL(gemm_kernel, dim3(64, 12), dim3(256), 0, stream,
                       x, BigB, BigBias, BigC);
    hipLaunchKernelGGL(sq_e_kernel, dim3(4096), dim3(256), 0, stream,
                       BigC, a, sq, e1, e2, xb);
    hipLaunchKernelGGL(dist_topk_kernel, dim3(64, 32), dim3(256), 0, stream,
                       xb, sq, candD, candI);
    hipLaunchKernelGGL(final_kernel, dim3(4096), dim3(256), 0, stream,
                       BigC, e1, e2, candD, candI, ln_g, ln_b, Wo, bo, out);
}

// Round 18
// 131.498 us; speedup vs baseline: 1.0401x; 1.0278x over previous
//
#include <hip/hip_runtime.h>
#include <math.h>

#define NTOK 4096
#define DIM 256
#define NHID 64
#define NHEADS 4
#define KSEL 6            // K+1
#define ALPHA_LR 0.2f
#define LNEPS 1e-5f
#define BIGN 768          // xm(256) | xr(256) | Wh(4*64)
#define JSPLIT 32         // 4096 / 128 j-tiles

typedef __attribute__((ext_vector_type(4))) float f32x4;
typedef __attribute__((ext_vector_type(8))) short short8;
typedef __attribute__((ext_vector_type(8))) unsigned short us8;
typedef unsigned long long ull;

__device__ __forceinline__ float f4get(const float4& v, int k) {
    return (k == 0) ? v.x : (k == 1) ? v.y : (k == 2) ? v.z : v.w;
}

__device__ __forceinline__ void gload16(const void* g, void* l) {
    __builtin_amdgcn_global_load_lds(
        (const __attribute__((address_space(1))) void*)g,
        (__attribute__((address_space(3))) void*)l, 16, 0, 0);
}

// u64 sorted-ascending top-6 insert; lex (key,idx) order via packed (ord<<32|j).
#define INS6U(L, V) do { ull _v = (V); if (_v < (L)[5]) {                         \
        bool c4 = _v < (L)[4], c3 = _v < (L)[3], c2 = _v < (L)[2];                \
        bool c1 = _v < (L)[1], c0 = _v < (L)[0];                                  \
        (L)[5] = c4 ? (L)[4] : _v;                                                \
        if (c4) { (L)[4] = c3 ? (L)[3] : _v; }                                    \
        if (c3) { (L)[3] = c2 ? (L)[2] : _v; }                                    \
        if (c2) { (L)[2] = c1 ? (L)[1] : _v; }                                    \
        if (c1) { (L)[1] = c0 ? (L)[0] : _v; }                                    \
        if (c0) { (L)[0] = _v; } } } while (0)

// ---------------- repack: BigB[256][768] = [Wm | Wr | W heads], BigBias[768] ----
__global__ void repack_kernel(const float* __restrict__ Wm, const float* __restrict__ bm,
                              const float* __restrict__ W,  const float* __restrict__ Wr,
                              const float* __restrict__ br,
                              float* __restrict__ BigB, float* __restrict__ BigBias) {
    int tid = blockIdx.x * blockDim.x + threadIdx.x;
    int total = DIM * BIGN;
    for (int e = tid; e < total; e += gridDim.x * blockDim.x) {
        int k = e / BIGN, col = e - k * BIGN;
        float v;
        if (col < 256)      v = Wm[k * 256 + col];
        else if (col < 512) v = Wr[k * 256 + (col - 256)];
        else {
            int c = col - 512;
            int h = c >> 6, d = c & 63;
            v = W[(h * DIM + k) * NHID + d];
        }
        BigB[e] = v;
    }
    if (tid < BIGN) {
        float b = 0.f;
        if (tid < 256)      b = bm[tid];
        else if (tid < 512) b = br[tid - 256];
        BigBias[tid] = b;
    }
}

// ---------------- GEMM: BigC[4096][768] = x[4096][256] @ BigB + BigBias --------
#define GEMM_SA 36
__global__ __launch_bounds__(256) void gemm_kernel(const float* __restrict__ A,
        const float* __restrict__ B, const float* __restrict__ bias,
        float* __restrict__ C) {
    __shared__ float As[64][GEMM_SA];   // [row][k]  (32 k used, pad to 36)
    __shared__ float Bs[32][64];        // [k][j]
    const int t  = threadIdx.x;
    const int tx = t & 15, ty = t >> 4;
    const int i0 = blockIdx.x * 64;
    const int j0 = blockIdx.y * 64;
    float c[4][4] = {};
    for (int kc = 0; kc < DIM / 32; ++kc) {
        __syncthreads();
        #pragma unroll
        for (int p = 0; p < 2; ++p) {
            int f  = t + p * 256;
            int ra = f >> 3, ka = (f & 7) * 4;
            *(float4*)&As[ra][ka] =
                *(const float4*)&A[(size_t)(i0 + ra) * DIM + kc * 32 + ka];
            int kb = f >> 4, jb = (f & 15) * 4;
            *(float4*)&Bs[kb][jb] =
                *(const float4*)&B[(size_t)(kc * 32 + kb) * BIGN + j0 + jb];
        }
        __syncthreads();
        #pragma unroll
        for (int kq = 0; kq < 8; ++kq) {
            float4 a4[4], b4[4];
            #pragma unroll
            for (int ii = 0; ii < 4; ++ii) a4[ii] = *(const float4*)&As[ty * 4 + ii][kq * 4];
            #pragma unroll
            for (int kk = 0; kk < 4; ++kk) b4[kk] = *(const float4*)&Bs[kq * 4 + kk][tx * 4];
            #pragma unroll
            for (int ii = 0; ii < 4; ++ii)
                #pragma unroll
                for (int kk = 0; kk < 4; ++kk)
                    #pragma unroll
                    for (int jj = 0; jj < 4; ++jj)
                        c[ii][jj] = fmaf(f4get(a4[ii], kk), f4get(b4[kk], jj), c[ii][jj]);
        }
    }
    #pragma unroll
    for (int ii = 0; ii < 4; ++ii) {
        int r = i0 + ty * 4 + ii;
        float4 bv = *(const float4*)&bias[j0 + tx * 4];
        float4 o;
        o.x = c[ii][0] + bv.x; o.y = c[ii][1] + bv.y;
        o.z = c[ii][2] + bv.z; o.w = c[ii][3] + bv.w;
        *(float4*)&C[(size_t)r * BIGN + j0 + tx * 4] = o;
    }
}

// ---------------- sq[n], e1[h][n], e2[h][n] + xb=[hi|lo] convert (fused) -------
__global__ __launch_bounds__(256) void sq_e_kernel(const float* __restrict__ BigC,
        const float* __restrict__ a, float* __restrict__ sq,
        float* __restrict__ e1, float* __restrict__ e2,
        unsigned short* __restrict__ xb) {
    const int n = blockIdx.x;
    const int t = threadIdx.x;
    const int l = t & 63;
    __shared__ float red[4];
    float xm = BigC[(size_t)n * BIGN + t];
    // bf16 hi/lo split (RNE both) -> xb
    {
        unsigned int u = __float_as_uint(xm);
        unsigned int hb = (u + 0x7fffu + ((u >> 16) & 1u)) >> 16;
        float hf = __uint_as_float(hb << 16);
        float lf = xm - hf;
        unsigned int u2 = __float_as_uint(lf);
        unsigned int lb = (u2 + 0x7fffu + ((u2 >> 16) & 1u)) >> 16;
        xb[(size_t)n * 512 + t]       = (unsigned short)hb;
        xb[(size_t)n * 512 + 256 + t] = (unsigned short)lb;
    }
    // sq: wave shfl reduce + 4-way
    float v = xm * xm;
    #pragma unroll
    for (int s = 32; s > 0; s >>= 1) v += __shfl_down(v, s, 64);
    if (l == 0) red[t >> 6] = v;
    __syncthreads();
    if (t == 0) sq[n] = red[0] + red[1] + red[2] + red[3];
    // e1/e2 per head (wave == head)
    const int h = t >> 6, d = t & 63;
    float wh = BigC[(size_t)n * BIGN + 512 + t];
    float v1 = wh * a[h * 128 + d];
    float v2 = wh * a[h * 128 + 64 + d];
    #pragma unroll
    for (int s = 32; s > 0; s >>= 1) {
        v1 += __shfl_down(v1, s, 64);
        v2 += __shfl_down(v2, s, 64);
    }
    if (d == 0) { e1[h * NTOK + n] = v1; e2[h * NTOK + n] = v2; }
}

// ---------------- distance GEMM: concat-K bf16x3, T3/T4 pipelined (R12) --------
// The session's verified optimum (99.6 us, measured x3).
// Tile 64i x 128j, 4 waves, 12 rounds of BK=64 (A'=[hi|lo|hi], B'=[hi|hi|lo]).
// LDS: 2 buffers x {A[64][64] 8KB + B[128][64] 16KB} = 48KB.
// Per round, per lane: 6 gload16 (prefetch r+2) + 12 ds_read_b128 + 16 MFMA.
// Protocol: vmcnt(6) [r==11: vmcnt(0)] -> s_barrier -> compute(buf[cur]) ->
// lgkmcnt(0)+sched_barrier -> s_barrier -> STAGE(r+2 -> buf[cur]).
// XOR swizzle both-sides: src chunk (l&7)^(l>>3), read (4s+l>>4)^(l&7).
__global__ __launch_bounds__(256, 2) void dist_topk_kernel(
        const unsigned short* __restrict__ xb, const float* __restrict__ sq,
        float* __restrict__ candD, int* __restrict__ candI) {
    __shared__ __align__(16) unsigned char smem[49664];
    unsigned short* sh = (unsigned short*)smem;   // 2 x 12288 shorts (48KB)
    float* Kd  = (float*)smem;                    // [32][132] epilogue overlay
    float* sqs = (float*)(smem + 49152);          // [128]

    const int t = threadIdx.x;
    const int l = t & 63;
    const int w = t >> 6;
    const int wi = w >> 1, wj = w & 1;            // wave tile 32i x 64j
    const int i0 = blockIdx.x * 64;
    const int j0 = blockIdx.y * 128;
    const int arow = l >> 3;
    const int csrc = ((l & 7) ^ (l >> 3)) * 8;    // pre-swizzled source chunk

    if (t < 32) ((float4*)sqs)[t] = ((const float4*)(sq + j0))[t];

    f32x4 acc[2][4] = {};

    #define STAGE(R, PAR) do {                                                    \
        const int _ac = (((R) < 8) ? (R) : (R) - 8) * 64;                         \
        const int _bc = (((R) < 4) ? (R) : (R) - 4) * 64;                         \
        unsigned short* _SA = sh + (PAR) * 12288;                                 \
        unsigned short* _SB = _SA + 4096;                                         \
        _Pragma("unroll")                                                         \
        for (int q = 0; q < 2; ++q) {                                             \
            const int rb = (w * 2 + q) * 8;                                       \
            gload16(xb + (size_t)(i0 + rb + arow) * 512 + _ac + csrc,             \
                    _SA + rb * 64);                                               \
        }                                                                         \
        _Pragma("unroll")                                                         \
        for (int q = 0; q < 4; ++q) {                                             \
            const int rb = (w * 4 + q) * 8;                                       \
            gload16(xb + (size_t)(j0 + rb + arow) * 512 + _bc + csrc,             \
                    _SB + rb * 64);                                               \
        }                                                                         \
    } while (0)

    // prologue: rounds 0 and 1 in flight
    STAGE(0, 0);
    STAGE(1, 1);

    #pragma unroll
    for (int r = 0; r < 12; ++r) {
        const int cur = r & 1;
        if (r < 11) { asm volatile("s_waitcnt vmcnt(6)" ::: "memory"); }
        else        { asm volatile("s_waitcnt vmcnt(0)" ::: "memory"); }
        __builtin_amdgcn_s_barrier();           // all waves' loads for buf[cur] landed
        {
            unsigned short* SA = sh + cur * 12288;
            unsigned short* SB = SA + 4096;
            #pragma unroll
            for (int s = 0; s < 2; ++s) {
                const int rsl = ((s * 4 + (l >> 4)) ^ (l & 7)) * 8;
                short8 af[2], bf[4];
                #pragma unroll
                for (int ti = 0; ti < 2; ++ti)
                    af[ti] = *(const short8*)(SA + (wi * 32 + ti * 16 + (l & 15)) * 64 + rsl);
                #pragma unroll
                for (int tj = 0; tj < 4; ++tj)
                    bf[tj] = *(const short8*)(SB + (wj * 64 + tj * 16 + (l & 15)) * 64 + rsl);
                #pragma unroll
                for (int ti = 0; ti < 2; ++ti)
                    #pragma unroll
                    for (int tj = 0; tj < 4; ++tj)
                        acc[ti][tj] = __builtin_amdgcn_mfma_f32_16x16x32_bf16(
                            af[ti], bf[tj], acc[ti][tj], 0, 0, 0);
            }
        }
        asm volatile("s_waitcnt lgkmcnt(0)" ::: "memory");  // my ds_reads complete
        __builtin_amdgcn_sched_barrier(0);
        __builtin_amdgcn_s_barrier();           // all waves done reading buf[cur]
        if (r + 2 < 12) STAGE(r + 2, cur);      // overwrite buf[cur] for round r+2
    }
    #undef STAGE

    // ---- epilogue: 2 passes of 32 i-rows; Kd overlay; u64 top-6 ---------------
    #pragma unroll
    for (int p = 0; p < 2; ++p) {
        __syncthreads();
        if (wi == p) {
            #pragma unroll
            for (int ti = 0; ti < 2; ++ti)
                #pragma unroll
                for (int tj = 0; tj < 4; ++tj) {
                    const int jb = wj * 64 + tj * 16 + (l & 15);
                    #pragma unroll
                    for (int r2 = 0; r2 < 4; ++r2)
                        Kd[(ti * 16 + ((l >> 4) << 2) + r2) * 132 + jb] = acc[ti][tj][r2];
                }
        }
        __syncthreads();
        {
            const int lr = t >> 3;
            const int jsl = (t & 7) * 16;
            ull L[6] = {~0ull, ~0ull, ~0ull, ~0ull, ~0ull, ~0ull};
            #pragma unroll
            for (int q4 = 0; q4 < 4; ++q4) {
                float4 dv = *(const float4*)&Kd[lr * 132 + jsl + q4 * 4];
                #pragma unroll
                for (int r2 = 0; r2 < 4; ++r2) {
                    const int jb = jsl + q4 * 4 + r2;
                    float key = sqs[jb] - 2.0f * f4get(dv, r2);
                    unsigned int u = __float_as_uint(key);
                    unsigned int o = (u & 0x80000000u) ? ~u : (u | 0x80000000u);
                    ull cand = ((ull)o << 32) | (unsigned int)(j0 + jb);
                    INS6U(L, cand);
                }
            }
            #pragma unroll
            for (int s2 = 1; s2 <= 4; s2 <<= 1) {
                ull ov[6];
                #pragma unroll
                for (int k = 0; k < 6; ++k) ov[k] = __shfl_xor(L[k], s2, 8);
                #pragma unroll
                for (int k = 0; k < 6; ++k) { INS6U(L, ov[k]); }
            }
            if ((t & 7) == 0) {
                const int r2 = p * 32 + lr;
                size_t ob = ((size_t)(i0 + r2) * JSPLIT + blockIdx.y) * KSEL;
                #pragma unroll
                for (int k = 0; k < 6; ++k) {
                    unsigned int o = (unsigned int)(L[k] >> 32);
                    unsigned int u = (o & 0x80000000u) ? (o ^ 0x80000000u) : ~o;
                    candD[ob + k] = __uint_as_float(u);
                    candI[ob + k] = (int)(L[k] & 0xffffffffu);
                }
            }
        }
    }
}

// ---------------- merge per-range top-6 -> global top-6 (32 lanes/row) ---------
__global__ __launch_bounds__(256) void merge_kernel(const float* __restrict__ candD,
        const int* __restrict__ candI, int* __restrict__ idx6) {
    int gid = blockIdx.x * 256 + threadIdx.x;      // 131072 threads
    int row = gid >> 5;
    int lg  = gid & 31;                            // lane's JSPLIT range
    size_t base = ((size_t)row * JSPLIT + lg) * KSEL;
    float d[KSEL]; int ix[KSEL];
    #pragma unroll
    for (int k = 0; k < KSEL; ++k) { d[k] = candD[base + k]; ix[k] = candI[base + k]; }
    float lastD = -3.0e38f; int lastI = -1;
    #pragma unroll
    for (int k = 0; k < KSEL; ++k) {
        float bdv = 3.4e38f; int biv = 0x7fffffff;
        #pragma unroll
        for (int q = 0; q < KSEL; ++q) {
            bool after  = (d[q] > lastD) || (d[q] == lastD && ix[q] > lastI);
            bool better = (d[q] < bdv)  || (d[q] == bdv  && ix[q] < biv);
            if (after && better) { bdv = d[q]; biv = ix[q]; }
        }
        #pragma unroll
        for (int s = 1; s < 32; s <<= 1) {
            float od = __shfl_xor(bdv, s, 32);
            int   oi = __shfl_xor(biv, s, 32);
            if (od < bdv || (od == bdv && oi < biv)) { bdv = od; biv = oi; }
        }
        if (lg == 0) idx6[row * KSEL + k] = biv;
        lastD = bdv; lastI = biv;
    }
}

// ---------------- attention + residual + LN + ELU + out projection -------------
__global__ __launch_bounds__(256) void final_kernel(const float* __restrict__ BigC,
        const float* __restrict__ e1, const float* __restrict__ e2,
        const int* __restrict__ idx6, const float* __restrict__ ln_g,
        const float* __restrict__ ln_b, const float* __restrict__ Wo,
        const float* __restrict__ bo, float* __restrict__ out) {
    const int i = blockIdx.x;
    const int t = threadIdx.x;
    const int h = t >> 6;
    const int l = t & 63;
    __shared__ int sidx[KSEL];
    __shared__ float red[4];
    if (t < KSEL) sidx[t] = idx6[i * KSEL + t];
    __syncthreads();
    const float e1i = e1[h * NTOK + i];
    float ev[KSEL];
    float m = -3.0e38f;
    #pragma unroll
    for (int k = 0; k < KSEL; ++k) {
        float v = e1i + e2[h * NTOK + sidx[k]];
        v = (v > 0.f) ? v : ALPHA_LR * v;
        ev[k] = v;
        m = fmaxf(m, v);
    }
    float ssum = 0.f;
    #pragma unroll
    for (int k = 0; k < KSEL; ++k) { ev[k] = expf(ev[k] - m); ssum += ev[k]; }
    float agg = 0.f;
    #pragma unroll
    for (int k = 0; k < KSEL; ++k)
        agg += ev[k] * BigC[(size_t)sidx[k] * BIGN + 512 + t];
    agg /= ssum;
    float hv = agg + BigC[(size_t)i * BIGN + 256 + t];
    // mean
    float v = hv;
    #pragma unroll
    for (int s = 32; s > 0; s >>= 1) v += __shfl_down(v, s, 64);
    if (l == 0) red[h] = v;
    __syncthreads();
    float mu = (red[0] + red[1] + red[2] + red[3]) * (1.f / 256.f);
    __syncthreads();
    // variance
    float dv = hv - mu;
    v = dv * dv;
    #pragma unroll
    for (int s = 32; s > 0; s >>= 1) v += __shfl_down(v, s, 64);
    if (l == 0) red[h] = v;
    __syncthreads();
    float var = (red[0] + red[1] + red[2] + red[3]) * (1.f / 256.f);
    __syncthreads();
    float nv  = dv / sqrtf(var + LNEPS) * ln_g[t] + ln_b[t];
    float act = (nv > 0.f) ? nv : expm1f(nv);
    // out0
    v = act * Wo[t * 2 + 0];
    #pragma unroll
    for (int s = 32; s > 0; s >>= 1) v += __shfl_down(v, s, 64);
    if (l == 0) red[h] = v;
    __syncthreads();
    float o0 = red[0] + red[1] + red[2] + red[3];
    __syncthreads();
    // out1
    v = act * Wo[t * 2 + 1];
    #pragma unroll
    for (int s = 32; s > 0; s >>= 1) v += __shfl_down(v, s, 64);
    if (l == 0) red[h] = v;
    __syncthreads();
    if (t == 0) {
        out[i * 2 + 0] = o0 + bo[0];
        out[i * 2 + 1] = red[0] + red[1] + red[2] + red[3] + bo[1];
    }
}

extern "C" void kernel_launch(void* const* d_in, const int* in_sizes, int n_in,
                              void* d_out, int out_size, void* d_ws, size_t ws_size,
                              hipStream_t stream) {
    (void)in_sizes; (void)n_in; (void)out_size; (void)ws_size;
    const float* x    = (const float*)d_in[0];
    const float* Wm   = (const float*)d_in[1];
    const float* bm   = (const float*)d_in[2];
    const float* W    = (const float*)d_in[3];
    const float* a    = (const float*)d_in[4];
    const float* Wr   = (const float*)d_in[5];
    const float* br   = (const float*)d_in[6];
    const float* ln_g = (const float*)d_in[7];
    const float* ln_b = (const float*)d_in[8];
    const float* Wo   = (const float*)d_in[9];
    const float* bo   = (const float*)d_in[10];
    float* out = (float*)d_out;

    char* ws = (char*)d_ws;
    float*          BigB    = (float*)(ws + 0);              // 786432 B
    float*          BigBias = (float*)(ws + 786432);         // -> 789504
    float*          BigC    = (float*)(ws + 789504);         // -> 13372416
    float*          sq      = (float*)(ws + 13372416);       // -> 13388800
    float*          e1      = (float*)(ws + 13388800);       // -> 13454336
    float*          e2      = (float*)(ws + 13454336);       // -> 13519872
    unsigned short* xb      = (unsigned short*)(ws + 13519872); // 4096*512*2 -> 17714176
    float*          candD   = (float*)(ws + 17714176);       // 4096*32*6*4 -> 20859904
    int*            candI   = (int*)  (ws + 20859904);       // -> 24005632
    int*            idx6    = (int*)  (ws + 24005632);       // -> 24103936

    hipLaunchKernelGGL(repack_kernel, dim3(768), dim3(256), 0, stream,
                       Wm, bm, W, Wr, br, BigB, BigBias);
    hipLaunchKernelGGL(gemm_kernel, dim3(64, 12), dim3(256), 0, stream,
                       x, BigB, BigBias, BigC);
    hipLaunchKernelGGL(sq_e_kernel, dim3(4096), dim3(256), 0, stream,
                       BigC, a, sq, e1, e2, xb);
    hipLaunchKernelGGL(dist_topk_kernel, dim3(64, 32), dim3(256), 0, stream,
                       xb, sq, candD, candI);
    hipLaunchKernelGGL(merge_kernel, dim3(512), dim3(256), 0, stream,
                       candD, candI, idx6);
    hipLaunchKernelGGL(final_kernel, dim3(4096), dim3(256), 0, stream,
                       BigC, e1, e2, idx6, ln_g, ln_b, Wo, bo, out);
}